// Round 9
// baseline (349.734 us; speedup 1.0000x reference)
//
#include <hip/hip_runtime.h>
#include <stdint.h>

typedef _Float16 f16;
typedef _Float16 half8 __attribute__((ext_vector_type(8)));
typedef _Float16 half4 __attribute__((ext_vector_type(4)));
typedef float floatx16 __attribute__((ext_vector_type(16)));

#define NIMG 3072

// ws byte offsets (all 16B-aligned)
#define WS_W0T   0           // f16 [7t][2hf][32co][8j]                  = 3,584
#define WS_W1T   10240       // f16 [25tap][2ch][2hf][32co][8j]          = 25,600
#define WS_W2T   61440       // f16 [16tap][2ch][2ct][2hf][32co][8j]     = 32,768
#define WS_W3T   126976      // f16 [36c][2ct][2hf][32col][8j]           = 36,864
#define WS_FC1T  200704      // f16 [6l][16c][4nt][2hf][32][8]           = 196,608
#define WS_FC2T  593920      // f16 [6l][8c][2nt][2hf][32][8]            = 49,152
#define WS_FC3T  692224      // f16 [6l][4c][2hf][32][8]                 = 12,288
#define WS_H3F   16646144    // f16 3072*1024, NHWC [16pos][64ci]

#define Z16 {0.f,0.f,0.f,0.f,0.f,0.f,0.f,0.f,0.f,0.f,0.f,0.f,0.f,0.f,0.f,0.f}

// conv0 dense-K tap offset (f16 units): tap = ky*5+kx, clamped to 24
#define TOF(t) ((((t) > 24 ? 24 : (t)) / 5) * 208 + (((t) > 24 ? 24 : (t)) % 5) * 4)

// ---------------- weight transform ----------------
__global__ __launch_bounds__(256) void k_prep(
    const float* __restrict__ w0, const float* __restrict__ w1, const float* __restrict__ w2,
    const float* __restrict__ w3, const float* __restrict__ fc1w, const float* __restrict__ fc2w,
    const float* __restrict__ fc3w,
    f16* __restrict__ w0t, f16* __restrict__ w1t, f16* __restrict__ w2t, f16* __restrict__ w3t,
    f16* __restrict__ fc1t, f16* __restrict__ fc2t, f16* __restrict__ fc3t)
{
  int stride = gridDim.x * blockDim.x;
  int g0 = blockIdx.x * blockDim.x + threadIdx.x;
  // conv0 dense K: k = t*16 + hf*8 + j -> tap = k>>2 (ky=tap/5,kx=tap%5), ci = k&3; zero for tap>=25
  for (int i = g0; i < 3584; i += stride) {
    int j = i & 7, co = (i >> 3) & 31, hf = (i >> 8) & 1, t = i >> 9;
    int k = t * 16 + hf * 8 + j, tap = k >> 2, ci = k & 3;
    f16 v = (f16)0.f;
    if (tap < 25) { int ky = tap / 5, kx = tap % 5; v = (f16)w0[((co * 4 + ci) * 5 + ky) * 5 + kx]; }
    w0t[i] = v;
  }
  for (int i = g0; i < 25600; i += stride) {
    int j = i & 7, co = (i >> 3) & 31, hf = (i >> 8) & 1, ch = (i >> 9) & 1, tap = i >> 10;
    int ci = ch * 16 + hf * 8 + j, ky = tap / 5, kx = tap % 5;
    w1t[i] = (f16)w1[((co * 32 + ci) * 5 + ky) * 5 + kx];
  }
  for (int i = g0; i < 32768; i += stride) {
    int j = i & 7, co = (i >> 3) & 31, hf = (i >> 8) & 1, ct = (i >> 9) & 1, ch = (i >> 10) & 1, tap = i >> 11;
    int ci = ch * 16 + hf * 8 + j, cog = ct * 32 + co, ky = tap >> 2, kx = tap & 3;
    w2t[i] = (f16)w2[((cog * 32 + ci) * 4 + ky) * 4 + kx];
  }
  // conv3: K = tap*64 + ci (tap = ky*3+kx, 9 taps, 64 ci -> 576 = 36 chunks)
  for (int i = g0; i < 36864; i += stride) {
    int j = i & 7, col = (i >> 3) & 31, hf = (i >> 8) & 1, ct = (i >> 9) & 1, c = i >> 10;
    int k = c * 16 + hf * 8 + j, tap = k >> 6, ci = k & 63, co = ct * 32 + col;
    int ky = tap / 3, kx = tap % 3;
    w3t[i] = (f16)w3[((co * 64 + ci) * 3 + ky) * 3 + kx];
  }
  // fc1: (L,256,128)
  for (int i = g0; i < 196608; i += stride) {
    int j = i & 7, col = (i >> 3) & 31, hf = (i >> 8) & 1, nt = (i >> 9) & 3, c = (i >> 11) & 15, l = i >> 15;
    int k = c * 16 + hf * 8 + j, o = nt * 32 + col;
    fc1t[i] = (f16)fc1w[(l * 256 + k) * 128 + o];
  }
  // fc2: (L,128,64)
  for (int i = g0; i < 49152; i += stride) {
    int j = i & 7, col = (i >> 3) & 31, hf = (i >> 8) & 1, nt = (i >> 9) & 1, c = (i >> 10) & 7, l = i >> 13;
    int k = c * 16 + hf * 8 + j, o = nt * 32 + col;
    fc2t[i] = (f16)fc2w[(l * 128 + k) * 64 + o];
  }
  // fc3: (L,64,4), cols >=4 zero
  for (int i = g0; i < 12288; i += stride) {
    int j = i & 7, col = (i >> 3) & 31, hf = (i >> 8) & 1, c = (i >> 9) & 3, l = i >> 11;
    int k = c * 16 + hf * 8 + j;
    f16 v = (f16)0.f;
    if (col < 4) v = (f16)fc3w[(l * 64 + k) * 4 + col];
    fc3t[i] = v;
  }
}

// ---------------- fused conv0+pool + conv1+pool + conv2+pool (MFMA f16) ----------------
// One image per block, full-image staging (R2 equilibrium: 65,312 B LDS, 2 blocks/CU).
// conv1 cell-packed (11 tiles, -31% MFMA, conflicts 2.7e7->1.5e7 measured R7).
// CRITICAL: the conv1 tile loop carries "#pragma unroll 1". Its natural trip count is
// 1-2; letting the compiler unroll it duplicates the 50-MFMA body and doubles every
// live range -> VGPR 48->120, occupancy 41%->21% (measured R7+R8, both forms). One
// rolled body restores the R2 register profile while keeping the cell-pack savings.
__global__ __launch_bounds__(512) void k_conv012(
    const float* __restrict__ x,
    const f16* __restrict__ w0t, const float* __restrict__ b0, const float* __restrict__ a0p,
    const f16* __restrict__ w1t, const float* __restrict__ b1, const float* __restrict__ a1p,
    const f16* __restrict__ w2t, const float* __restrict__ b2, const float* __restrict__ a2p,
    f16* __restrict__ h3f)
{
  __shared__ __align__(16) uint32_t smem_u[16328];   // 65,312 B -> 2 blocks/CU
  f16* sh   = (f16*)smem_u;
  f16* s_x  = sh;           // [47][52][4] = 9776 f16; reused later as s2 [12][14][40] = 6720 f16
  f16* s_h1 = sh + 9776;    // [22][26][40] = 22880 f16 (word base 4888)

  const int n = blockIdx.x, tid = threadIdx.x;
  const int wv = tid >> 6, l = tid & 63;
  const int hf = l >> 5, m = l & 31, dr = m >> 3, dc = m & 7, col = m;
  const float a0 = a0p[0], a1 = a1p[0];
  const float b0c = b0[col], b1c = b1[col];
  const half8* w0t8 = (const half8*)w0t;
  const half8* w1t8 = (const half8*)w1t;
  const half8* w2t8 = (const half8*)w2t;

  // ---- targeted pad zeroing (interiors get fully overwritten; ch>=32 lane-pad never read) ----
  // s_x pads: row 0 (104 w) + rows 1..45 x cols {0, 46..51} (14 w/row) = 734 words
  for (int i = tid; i < 734; i += 512) {
    int w;
    if (i < 104) w = i;
    else { int j = i - 104; int r = j / 14 + 1, c = j % 14; w = r * 104 + (c < 2 ? c : 90 + c); }
    smem_u[w] = 0u;
  }
  // s_h1 pads: row 0 cols 0..25 + rows 1..21 x cols {0,22,23,24,25}; 16 words/cell (ch0..31)
  for (int i = tid; i < 2096; i += 512) {
    int cell = i >> 4, wi = i & 15, r, c;
    if (cell < 26) { r = 0; c = cell; }
    else { int j = cell - 26; r = j / 5 + 1; int c5 = j % 5; c = (c5 == 0) ? 0 : 21 + c5; }
    smem_u[4888 + (r * 26 + c) * 20 + wi] = 0u;
  }
  // vectorized staging: 4 coalesced f32 streams -> one b64 LDS write per pixel
  const float* xin = x + n * 8100;
  for (int p = tid; p < 2025; p += 512) {
    int y = p / 45, xx = p % 45;
    half4 h;
    h[0] = (f16)xin[p];
    h[1] = (f16)xin[p + 2025];
    h[2] = (f16)xin[p + 4050];
    h[3] = (f16)xin[p + 6075];
    *(half4*)(s_x + ((y + 1) * 52 + (xx + 1)) * 4) = h;
  }
  __syncthreads();

  half8 B0[7];
  #pragma unroll
  for (int q = 0; q < 7; ++q)
    B0[q] = w0t8[(q * 2 + hf) * 32 + col];

  // ---- conv0: dense K (7 chunks of 16 = taps 0..24 x ci 0..3), conflict-free lane remap ----
  // pixel row = m0 + 2*m3, pixel col = m1 + 2*m2 + 4*m4 (bank-perfect for b64 reads)
  const int cdr = (m & 1) | ((m & 8) >> 2);
  const int cdc = ((m >> 1) & 3) | ((m & 16) >> 2);
  for (int t = wv; t < 66; t += 8) {
    int g = t / 6;
    int r0 = 4 * g; if (r0 > 38) r0 = 38;
    int cb = (t % 6) * 8;
    int rowb = r0 + cdr, colb = cb + cdc;
    const f16* base = s_x + (rowb * 52 + colb) * 4;
    floatx16 acc = Z16;
    #pragma unroll
    for (int q = 0; q < 7; ++q) {
      const int offL = hf ? TOF(4 * q + 2) : TOF(4 * q);
      half4 lo4 = *(const half4*)(base + offL);
      half4 hi4;
      if (q < 6) {
        const int offH = hf ? TOF(4 * q + 3) : TOF(4 * q + 1);
        hi4 = *(const half4*)(base + offH);
      } else {
        hi4 = (half4){(f16)0, (f16)0, (f16)0, (f16)0};   // taps >= 25: B is zero
      }
      half8 av = __builtin_shufflevector(lo4, hi4, 0, 1, 2, 3, 4, 5, 6, 7);
      acc = __builtin_amdgcn_mfma_f32_32x32x16_f16(av, B0[q], acc, 0, 0, 0);
    }
    // D row p = (reg&3) + 8*(reg>>2) + 4*hf; with the remap, pooling = max over reg&3.
    #pragma unroll
    for (int q = 0; q < 4; ++q) {
      float v = fmaxf(fmaxf(acc[4*q], acc[4*q + 1]), fmaxf(acc[4*q + 2], acc[4*q + 3]));
      v += b0c; v = (v >= 0.f) ? v : a0 * v;
      int pr = (r0 >> 1) + (q & 1), pc = (cb >> 1) + hf + 2 * (q >> 1);
      if (pc < 21) s_h1[((pr + 1) * 26 + (pc + 1)) * 40 + col] = (f16)v;
    }
  }
  __syncthreads();   // conv0 done: s_x dead, s_h1 complete

  // zero s2 pads (s2 [12][14][40] overlays dead s_x region): rows {0,10} cols 0..10,
  // rows 1..9 cols {0,10}, ch0..31  (disjoint from s_h1 and from s2 interiors)
  f16* s2 = s_x;
  for (int i = tid; i < 640; i += 512) {
    int cell = i >> 4, wi = i & 15, r, c;
    if (cell < 11)      { r = 0;  c = cell; }
    else if (cell < 22) { r = 10; c = cell - 11; }
    else if (cell < 31) { r = cell - 21; c = 0; }
    else                { r = cell - 30; c = 10; }
    smem_u[(r * 14 + c) * 20 + wi] = 0u;
  }

  // ---- conv1: pool-cell-packed tiles, single-acc ROLLED loop, immediate s2 writes ----
  // Effective conv-out 18x18 = 81 pool cells of 2x2. Tile t covers cells e=8t..8t+7
  // (11 tiles; wave wv takes t=wv and, for wv<3, t=wv+8). A-row p=m: q=m&3,
  // e = 8t+(m>>2); (er,ec)=(e*57>>9, e-9*er); pos (2er+(q>>1), 2ec+(q&1)).
  // D reg-quad u pools cell e = 8t + 2u + hf -> s2[er+1][ec+1][col].
  const int q_ = m & 3, gcell = m >> 2;
  #pragma unroll 1
  for (int t = wv; t < 11; t += 8) {
    int e = 8 * t + gcell; if (e > 80) e = 80;      // tile 10: cells 81..87 clamp (discarded)
    int er = (e * 57) >> 9, ec = e - 9 * er;
    int rm = 2 * er + (q_ >> 1), cm = 2 * ec + (q_ & 1);
    const f16* pA = s_h1 + (rm * 26 + cm) * 40 + hf * 8;
    floatx16 acc = Z16;
    for (int ky = 0; ky < 5; ++ky) {
      const half8* wb = w1t8 + ky * 640 + hf * 32 + col;
      const f16* qa = pA + ky * 1040;
      #pragma unroll
      for (int kx = 0; kx < 5; ++kx) {
        #pragma unroll
        for (int ch = 0; ch < 2; ++ch) {
          half8 b = wb[kx * 128 + ch * 64];
          half8 a = *(const half8*)(qa + kx * 40 + ch * 16);
          acc = __builtin_amdgcn_mfma_f32_32x32x16_f16(a, b, acc, 0, 0, 0);
        }
      }
    }
    #pragma unroll 1
    for (int u = 0; u < 4; ++u) {
      int ed = 8 * t + 2 * u + hf;
      if (ed <= 80) {
        float v = fmaxf(fmaxf(acc[4*u], acc[4*u + 1]), fmaxf(acc[4*u + 2], acc[4*u + 3]));
        v += b1c; v = (v >= 0.f) ? v : a1 * v;
        int er2 = (ed * 57) >> 9, ec2 = ed - 9 * er2;
        s2[((er2 + 1) * 14 + (ec2 + 1)) * 40 + col] = (f16)v;
      }
    }
  }
  __syncthreads();   // s2 (pads + interiors) complete

  // ---- conv2+pool: 4 waves = (row-half mt, co-tile c2t); write h3f NHWC ----
  // s2 row stride 14 cells: b128 bank groups (6dr+5dc) mod 8 -> perfect 4-per-group
  if (wv < 4) {
    const int mt = wv >> 1, c2t = wv & 1;
    const float a2 = a2p[0];
    const float b2c = b2[c2t * 32 + col];
    const f16* pA = s2 + ((mt * 4 + dr) * 14 + dc) * 40 + hf * 8;
    floatx16 acc = Z16;
    #pragma unroll 4
    for (int tap = 0; tap < 16; ++tap) {
      int aoff = ((tap >> 2) * 14 + (tap & 3)) * 40;
      #pragma unroll
      for (int ch = 0; ch < 2; ++ch) {
        half8 b = w2t8[tap * 256 + ch * 128 + c2t * 64 + hf * 32 + col];
        half8 a = *(const half8*)(pA + aoff + ch * 16);
        acc = __builtin_amdgcn_mfma_f32_32x32x16_f16(a, b, acc, 0, 0, 0);
      }
    }
    f16* o = h3f + n * 1024;
    #pragma unroll
    for (int pp = 0; pp < 2; ++pp)
      #pragma unroll
      for (int c2 = 0; c2 < 2; ++c2) {
        float v = fmaxf(fmaxf(acc[8*pp + 2*c2], acc[8*pp + 2*c2 + 1]),
                        fmaxf(acc[8*pp + 4 + 2*c2], acc[8*pp + 4 + 2*c2 + 1]));
        v += b2c; v = (v >= 0.f) ? v : a2 * v;
        int pr = mt * 2 + pp, pc = 2 * hf + c2;
        o[(pr * 4 + pc) * 64 + c2t * 32 + col] = (f16)v;
      }
  }
}

// ---------------- fused conv3 + fc1 + fc2 + fc3 (MFMA f16) ----------------
// grid 96: blockIdx -> landmark l = b%6, image tile t = b/6 (32 images, n = (32t+i)*6+l)
__global__ __launch_bounds__(256) void k_tail(
    const f16* __restrict__ h3f,
    const f16* __restrict__ w3t, const float* __restrict__ b3, const float* __restrict__ a3p,
    const f16* __restrict__ fc1t, const float* __restrict__ fc1b, const float* __restrict__ a4,
    const f16* __restrict__ fc2t, const float* __restrict__ fc2b, const float* __restrict__ a5,
    const f16* __restrict__ fc3t, const float* __restrict__ fc3b,
    float* __restrict__ out)
{
  __shared__ __align__(16) f16 s_feat[32 * 264];  // row stride 264 f16 (528B: bank-start stride 4 -> b128 conflict-free)
  __shared__ __align__(16) f16 s_g1[32 * 136];
  __shared__ __align__(16) f16 s_g2[32 * 72];

  const int lm = blockIdx.x % 6, t = blockIdx.x / 6;
  const int tid = threadIdx.x, wv = tid >> 6, lane = tid & 63;
  const int hf = lane >> 5, col = lane & 31;
  const half8* w3t8  = (const half8*)w3t;
  const half8* fc1t8 = (const half8*)fc1t;
  const half8* fc2t8 = (const half8*)fc2t;
  const half8* fc3t8 = (const half8*)fc3t;

  // ---- conv3: wave = M-tile (8 images x 4 positions); K=576 (36 chunks); N=64 (2 ct) ----
  {
    const int mt = wv;
    const int i_img = mt * 8 + (col >> 2);
    const int pos = col & 3, oy = pos >> 1, ox = pos & 1;
    const int gimg = (t * 32 + i_img) * 6 + lm;
    const f16* Abase = h3f + gimg * 1024 + (oy * 4 + ox) * 64;
    floatx16 acc0 = Z16, acc1 = Z16;
    for (int c = 0; c < 36; ++c) {
      int tap = c >> 2;
      int ky = tap / 3, kx = tap % 3;
      half8 a = *(const half8*)(Abase + (ky * 4 + kx) * 64 + (c & 3) * 16 + hf * 8);
      half8 bb0 = w3t8[((c * 2 + 0) * 2 + hf) * 32 + col];
      half8 bb1 = w3t8[((c * 2 + 1) * 2 + hf) * 32 + col];
      acc0 = __builtin_amdgcn_mfma_f32_32x32x16_f16(a, bb0, acc0, 0, 0, 0);
      acc1 = __builtin_amdgcn_mfma_f32_32x32x16_f16(a, bb1, acc1, 0, 0, 0);
    }
    const float a3 = a3p[0];
    #pragma unroll
    for (int ct = 0; ct < 2; ++ct) {
      const floatx16 acc = ct ? acc1 : acc0;
      const int co = ct * 32 + col;
      const float bb = b3[co];
      #pragma unroll
      for (int q = 0; q < 4; ++q) {
        int ii = mt * 8 + 2 * q + hf;
        half4 w;
        #pragma unroll
        for (int z = 0; z < 4; ++z) {
          float v = acc[q * 4 + z] + bb;
          v = (v >= 0.f) ? v : a3 * v;
          w[z] = (f16)v;
        }
        *(half4*)(s_feat + ii * 264 + co * 4) = w;
      }
    }
  }
  __syncthreads();

  // ---- fc1: M=32 imgs, K=256 (16 chunks), N=128; wave = N-tile ----
  {
    floatx16 g = Z16;
    for (int c = 0; c < 16; ++c) {
      half8 a = *(const half8*)(s_feat + col * 264 + c * 16 + hf * 8);
      half8 b = fc1t8[(((lm * 16 + c) * 4 + wv) * 2 + hf) * 32 + col];
      g = __builtin_amdgcn_mfma_f32_32x32x16_f16(a, b, g, 0, 0, 0);
    }
    const float a4v = a4[lm];
    const float bb = fc1b[lm * 128 + wv * 32 + col];
    #pragma unroll
    for (int reg = 0; reg < 16; ++reg) {
      int r = (reg & 3) + 8 * (reg >> 2) + 4 * hf;
      float v = g[reg] + bb;
      v = (v >= 0.f) ? v : a4v * v;
      s_g1[r * 136 + wv * 32 + col] = (f16)v;
    }
  }
  __syncthreads();

  // ---- fc2: K=128 (8 chunks), N=64; waves 0,1 ----
  if (wv < 2) {
    floatx16 g = Z16;
    for (int c = 0; c < 8; ++c) {
      half8 a = *(const half8*)(s_g1 + col * 136 + c * 16 + hf * 8);
      half8 b = fc2t8[(((lm * 8 + c) * 2 + wv) * 2 + hf) * 32 + col];
      g = __builtin_amdgcn_mfma_f32_32x32x16_f16(a, b, g, 0, 0, 0);
    }
    const float a5v = a5[lm];
    const float bb = fc2b[lm * 64 + wv * 32 + col];
    #pragma unroll
    for (int reg = 0; reg < 16; ++reg) {
      int r = (reg & 3) + 8 * (reg >> 2) + 4 * hf;
      float v = g[reg] + bb;
      v = (v >= 0.f) ? v : a5v * v;
      s_g2[r * 72 + wv * 32 + col] = (f16)v;
    }
  }
  __syncthreads();

  // ---- fc3: K=64 (4 chunks), N=4 (padded); wave 0 ----
  if (wv == 0) {
    floatx16 g = Z16;
    for (int c = 0; c < 4; ++c) {
      half8 a = *(const half8*)(s_g2 + col * 72 + c * 16 + hf * 8);
      half8 b = fc3t8[((lm * 4 + c) * 2 + hf) * 32 + col];
      g = __builtin_amdgcn_mfma_f32_32x32x16_f16(a, b, g, 0, 0, 0);
    }
    if (col < 4) {
      const float bb = fc3b[lm * 4 + col];
      #pragma unroll
      for (int reg = 0; reg < 16; ++reg) {
        int r = (reg & 3) + 8 * (reg >> 2) + 4 * hf;
        out[((t * 32 + r) * 6 + lm) * 4 + col] = g[reg] + bb;
      }
    }
  }
}

extern "C" void kernel_launch(void* const* d_in, const int* in_sizes, int n_in,
                              void* d_out, int out_size, void* d_ws, size_t ws_size,
                              hipStream_t stream) {
  const float* x    = (const float*)d_in[0];
  const float* w0   = (const float*)d_in[1];
  const float* b0   = (const float*)d_in[2];
  const float* w1   = (const float*)d_in[3];
  const float* b1   = (const float*)d_in[4];
  const float* w2   = (const float*)d_in[5];
  const float* b2   = (const float*)d_in[6];
  const float* w3   = (const float*)d_in[7];
  const float* b3   = (const float*)d_in[8];
  const float* a0   = (const float*)d_in[9];
  const float* a1   = (const float*)d_in[10];
  const float* a2   = (const float*)d_in[11];
  const float* a3   = (const float*)d_in[12];
  const float* fc1w = (const float*)d_in[13];
  const float* fc1b = (const float*)d_in[14];
  const float* a4   = (const float*)d_in[15];
  const float* fc2w = (const float*)d_in[16];
  const float* fc2b = (const float*)d_in[17];
  const float* a5   = (const float*)d_in[18];
  const float* fc3w = (const float*)d_in[19];
  const float* fc3b = (const float*)d_in[20];
  float* out = (float*)d_out;

  char* ws = (char*)d_ws;
  f16* w0t  = (f16*)(ws + WS_W0T);
  f16* w1t  = (f16*)(ws + WS_W1T);
  f16* w2t  = (f16*)(ws + WS_W2T);
  f16* w3t  = (f16*)(ws + WS_W3T);
  f16* fc1t = (f16*)(ws + WS_FC1T);
  f16* fc2t = (f16*)(ws + WS_FC2T);
  f16* fc3t = (f16*)(ws + WS_FC3T);
  f16* h3f  = (f16*)(ws + WS_H3F);

  k_prep   <<<128, 256, 0, stream>>>(w0, w1, w2, w3, fc1w, fc2w, fc3w,
                                     w0t, w1t, w2t, w3t, fc1t, fc2t, fc3t);
  k_conv012<<<NIMG, 512, 0, stream>>>(x, w0t, b0, a0, w1t, b1, a1, w2t, b2, a2, h3f);
  k_tail   <<<96, 256, 0, stream>>>(h3f, w3t, b3, a3, fc1t, fc1b, a4,
                                    fc2t, fc2b, a5, fc3t, fc3b, out);
}

// Round 10
// 316.951 us; speedup vs baseline: 1.1034x; 1.1034x over previous
//
#include <hip/hip_runtime.h>
#include <stdint.h>

typedef _Float16 f16;
typedef _Float16 half8 __attribute__((ext_vector_type(8)));
typedef _Float16 half4 __attribute__((ext_vector_type(4)));
typedef float floatx16 __attribute__((ext_vector_type(16)));

#define NIMG 3072

// ws byte offsets (all 16B-aligned)
#define WS_W0T   0           // f16 [7t][2hf][32co][8j]                  = 3,584
#define WS_W1T   10240       // f16 [25tap][2ch][2hf][32co][8j]          = 25,600
#define WS_W2T   61440       // f16 [16tap][2ch][2ct][2hf][32co][8j]     = 32,768
#define WS_W3T   126976      // f16 [36c][2ct][2hf][32col][8j]           = 36,864
#define WS_FC1T  200704      // f16 [6l][16c][4nt][2hf][32][8]           = 196,608
#define WS_FC2T  593920      // f16 [6l][8c][2nt][2hf][32][8]            = 49,152
#define WS_FC3T  692224      // f16 [6l][4c][2hf][32][8]                 = 12,288
#define WS_H3F   16646144    // f16 3072*1024, NHWC [16pos][64ci]

#define Z16 {0.f,0.f,0.f,0.f,0.f,0.f,0.f,0.f,0.f,0.f,0.f,0.f,0.f,0.f,0.f,0.f}

// conv0 dense-K tap offset (f16 units): tap = ky*5+kx, clamped to 24
#define TOF(t) ((((t) > 24 ? 24 : (t)) / 5) * 208 + (((t) > 24 ? 24 : (t)) % 5) * 4)

// ---------------- weight transform ----------------
__global__ __launch_bounds__(256) void k_prep(
    const float* __restrict__ w0, const float* __restrict__ w1, const float* __restrict__ w2,
    const float* __restrict__ w3, const float* __restrict__ fc1w, const float* __restrict__ fc2w,
    const float* __restrict__ fc3w,
    f16* __restrict__ w0t, f16* __restrict__ w1t, f16* __restrict__ w2t, f16* __restrict__ w3t,
    f16* __restrict__ fc1t, f16* __restrict__ fc2t, f16* __restrict__ fc3t)
{
  int stride = gridDim.x * blockDim.x;
  int g0 = blockIdx.x * blockDim.x + threadIdx.x;
  // conv0 dense K: k = t*16 + hf*8 + j -> tap = k>>2 (ky=tap/5,kx=tap%5), ci = k&3; zero for tap>=25
  for (int i = g0; i < 3584; i += stride) {
    int j = i & 7, co = (i >> 3) & 31, hf = (i >> 8) & 1, t = i >> 9;
    int k = t * 16 + hf * 8 + j, tap = k >> 2, ci = k & 3;
    f16 v = (f16)0.f;
    if (tap < 25) { int ky = tap / 5, kx = tap % 5; v = (f16)w0[((co * 4 + ci) * 5 + ky) * 5 + kx]; }
    w0t[i] = v;
  }
  for (int i = g0; i < 25600; i += stride) {
    int j = i & 7, co = (i >> 3) & 31, hf = (i >> 8) & 1, ch = (i >> 9) & 1, tap = i >> 10;
    int ci = ch * 16 + hf * 8 + j, ky = tap / 5, kx = tap % 5;
    w1t[i] = (f16)w1[((co * 32 + ci) * 5 + ky) * 5 + kx];
  }
  for (int i = g0; i < 32768; i += stride) {
    int j = i & 7, co = (i >> 3) & 31, hf = (i >> 8) & 1, ct = (i >> 9) & 1, ch = (i >> 10) & 1, tap = i >> 11;
    int ci = ch * 16 + hf * 8 + j, cog = ct * 32 + co, ky = tap >> 2, kx = tap & 3;
    w2t[i] = (f16)w2[((cog * 32 + ci) * 4 + ky) * 4 + kx];
  }
  // conv3: K = tap*64 + ci (tap = ky*3+kx, 9 taps, 64 ci -> 576 = 36 chunks)
  for (int i = g0; i < 36864; i += stride) {
    int j = i & 7, col = (i >> 3) & 31, hf = (i >> 8) & 1, ct = (i >> 9) & 1, c = i >> 10;
    int k = c * 16 + hf * 8 + j, tap = k >> 6, ci = k & 63, co = ct * 32 + col;
    int ky = tap / 3, kx = tap % 3;
    w3t[i] = (f16)w3[((co * 64 + ci) * 3 + ky) * 3 + kx];
  }
  // fc1: (L,256,128)
  for (int i = g0; i < 196608; i += stride) {
    int j = i & 7, col = (i >> 3) & 31, hf = (i >> 8) & 1, nt = (i >> 9) & 3, c = (i >> 11) & 15, l = i >> 15;
    int k = c * 16 + hf * 8 + j, o = nt * 32 + col;
    fc1t[i] = (f16)fc1w[(l * 256 + k) * 128 + o];
  }
  // fc2: (L,128,64)
  for (int i = g0; i < 49152; i += stride) {
    int j = i & 7, col = (i >> 3) & 31, hf = (i >> 8) & 1, nt = (i >> 9) & 1, c = (i >> 10) & 7, l = i >> 13;
    int k = c * 16 + hf * 8 + j, o = nt * 32 + col;
    fc2t[i] = (f16)fc2w[(l * 128 + k) * 64 + o];
  }
  // fc3: (L,64,4), cols >=4 zero
  for (int i = g0; i < 12288; i += stride) {
    int j = i & 7, col = (i >> 3) & 31, hf = (i >> 8) & 1, c = (i >> 9) & 3, l = i >> 11;
    int k = c * 16 + hf * 8 + j;
    f16 v = (f16)0.f;
    if (col < 4) v = (f16)fc3w[(l * 64 + k) * 4 + col];
    fc3t[i] = v;
  }
}

// ---------------- fused conv0+pool + conv1+pool + conv2+pool (MFMA f16) ----------------
// EXACT Round-2 form (verified: 166.1 us, VGPR 52, total 318.6). The cell-packed conv1
// arc (R7-R9) is closed: that body allocates 120 VGPR in every form tried (two inlined
// bodies, rolled loop, pragma-rolled loop) -> 21% occupancy -> net loss. Do not revisit
// without disasm evidence of the allocation source.
__global__ __launch_bounds__(512) void k_conv012(
    const float* __restrict__ x,
    const f16* __restrict__ w0t, const float* __restrict__ b0, const float* __restrict__ a0p,
    const f16* __restrict__ w1t, const float* __restrict__ b1, const float* __restrict__ a1p,
    const f16* __restrict__ w2t, const float* __restrict__ b2, const float* __restrict__ a2p,
    f16* __restrict__ h3f)
{
  __shared__ __align__(16) uint32_t smem_u[16328];   // 65,312 B -> 2 blocks/CU
  f16* sh   = (f16*)smem_u;
  f16* s_x  = sh;           // [47][52][4] = 9776 f16; reused later as s2 [12][12][40] = 5760 f16
  f16* s_h1 = sh + 9776;    // [22][26][40] = 22880 f16 (word base 4888)

  const int n = blockIdx.x, tid = threadIdx.x;
  const int wv = tid >> 6, l = tid & 63;
  const int hf = l >> 5, m = l & 31, dr = m >> 3, dc = m & 7, col = m;
  const float a0 = a0p[0], a1 = a1p[0];
  const float b0c = b0[col], b1c = b1[col];
  const half8* w0t8 = (const half8*)w0t;
  const half8* w1t8 = (const half8*)w1t;
  const half8* w2t8 = (const half8*)w2t;

  // ---- targeted pad zeroing (interiors get fully overwritten; ch>=32 lane-pad never read) ----
  // s_x pads: row 0 (104 w) + rows 1..45 x cols {0, 46..51} (14 w/row) = 734 words
  for (int i = tid; i < 734; i += 512) {
    int w;
    if (i < 104) w = i;
    else { int j = i - 104; int r = j / 14 + 1, c = j % 14; w = r * 104 + (c < 2 ? c : 90 + c); }
    smem_u[w] = 0u;
  }
  // s_h1 pads: row 0 cols 0..25 + rows 1..21 x cols {0,22,23,24,25}; 16 words/cell (ch0..31)
  for (int i = tid; i < 2096; i += 512) {
    int cell = i >> 4, wi = i & 15, r, c;
    if (cell < 26) { r = 0; c = cell; }
    else { int j = cell - 26; r = j / 5 + 1; int c5 = j % 5; c = (c5 == 0) ? 0 : 21 + c5; }
    smem_u[4888 + (r * 26 + c) * 20 + wi] = 0u;
  }
  // vectorized staging: 4 coalesced f32 streams -> one b64 LDS write per pixel
  const float* xin = x + n * 8100;
  for (int p = tid; p < 2025; p += 512) {
    int y = p / 45, xx = p % 45;
    half4 h;
    h[0] = (f16)xin[p];
    h[1] = (f16)xin[p + 2025];
    h[2] = (f16)xin[p + 4050];
    h[3] = (f16)xin[p + 6075];
    *(half4*)(s_x + ((y + 1) * 52 + (xx + 1)) * 4) = h;
  }
  __syncthreads();

  half8 B0[7];
  #pragma unroll
  for (int q = 0; q < 7; ++q)
    B0[q] = w0t8[(q * 2 + hf) * 32 + col];

  // ---- conv0: dense K (7 chunks of 16 = taps 0..24 x ci 0..3), conflict-free lane remap ----
  // pixel row = m0 + 2*m3, pixel col = m1 + 2*m2 + 4*m4 (bank-perfect for b64 reads)
  const int cdr = (m & 1) | ((m & 8) >> 2);
  const int cdc = ((m >> 1) & 3) | ((m & 16) >> 2);
  for (int t = wv; t < 66; t += 8) {
    int g = t / 6;
    int r0 = 4 * g; if (r0 > 38) r0 = 38;
    int cb = (t % 6) * 8;
    int rowb = r0 + cdr, colb = cb + cdc;
    const f16* base = s_x + (rowb * 52 + colb) * 4;
    floatx16 acc = Z16;
    #pragma unroll
    for (int q = 0; q < 7; ++q) {
      const int offL = hf ? TOF(4 * q + 2) : TOF(4 * q);
      half4 lo4 = *(const half4*)(base + offL);
      half4 hi4;
      if (q < 6) {
        const int offH = hf ? TOF(4 * q + 3) : TOF(4 * q + 1);
        hi4 = *(const half4*)(base + offH);
      } else {
        hi4 = (half4){(f16)0, (f16)0, (f16)0, (f16)0};   // taps >= 25: B is zero
      }
      half8 av = __builtin_shufflevector(lo4, hi4, 0, 1, 2, 3, 4, 5, 6, 7);
      acc = __builtin_amdgcn_mfma_f32_32x32x16_f16(av, B0[q], acc, 0, 0, 0);
    }
    // D row p = (reg&3) + 8*(reg>>2) + 4*hf; with the remap, pooling = max over reg&3.
    #pragma unroll
    for (int q = 0; q < 4; ++q) {
      float v = fmaxf(fmaxf(acc[4*q], acc[4*q + 1]), fmaxf(acc[4*q + 2], acc[4*q + 3]));
      v += b0c; v = (v >= 0.f) ? v : a0 * v;
      int pr = (r0 >> 1) + (q & 1), pc = (cb >> 1) + hf + 2 * (q >> 1);
      if (pc < 21) s_h1[((pr + 1) * 26 + (pc + 1)) * 40 + col] = (f16)v;
    }
  }
  __syncthreads();

  // zero s2 pads (s2 [12][12][40] overlays dead s_x region): rows {0,10}, cols {0,10}, ch0..31
  for (int i = tid; i < 640; i += 512) {
    int cell = i >> 4, wi = i & 15, r, c;
    if (cell < 11)      { r = 0;  c = cell; }
    else if (cell < 22) { r = 10; c = cell - 11; }
    else if (cell < 31) { r = cell - 21; c = 0; }
    else                { r = cell - 30; c = 10; }
    smem_u[(r * 12 + c) * 20 + wi] = 0u;
  }

  // ---- conv1 ----
  int t0 = wv * 2;
  int t1 = t0 + 1; if (t1 > 14) t1 = 14;
  int r0a = 4 * (t0 / 3); if (r0a > 14) r0a = 14;
  int cca = 8 * (t0 % 3); if (cca > 14) cca = 14;
  int r0b = 4 * (t1 / 3); if (r0b > 14) r0b = 14;
  int ccb = 8 * (t1 % 3); if (ccb > 14) ccb = 14;
  const f16* pAa = s_h1 + ((r0a + dr) * 26 + cca + dc) * 40 + hf * 8;
  const f16* pAb = s_h1 + ((r0b + dr) * 26 + ccb + dc) * 40 + hf * 8;
  floatx16 accA = Z16;
  floatx16 accB = Z16;
  for (int ky = 0; ky < 5; ++ky) {
    const half8* wb = w1t8 + ky * 640 + hf * 32 + col;
    const f16* qa = pAa + ky * 1040;
    const f16* qb = pAb + ky * 1040;
    #pragma unroll
    for (int kx = 0; kx < 5; ++kx) {
      #pragma unroll
      for (int ch = 0; ch < 2; ++ch) {
        half8 b  = wb[kx * 128 + ch * 64];
        half8 aA = *(const half8*)(qa + kx * 40 + ch * 16);
        half8 aB = *(const half8*)(qb + kx * 40 + ch * 16);
        accA = __builtin_amdgcn_mfma_f32_32x32x16_f16(aA, b, accA, 0, 0, 0);
        accB = __builtin_amdgcn_mfma_f32_32x32x16_f16(aB, b, accB, 0, 0, 0);
      }
    }
  }
  __syncthreads();   // s2 pad zero complete; s_h1 reads done

  f16* s2 = s_x;
  #pragma unroll
  for (int tt = 0; tt < 2; ++tt) {
    const floatx16 acc = tt ? accB : accA;
    int r0 = tt ? r0b : r0a, cc = tt ? ccb : cca;
    #pragma unroll
    for (int pp = 0; pp < 2; ++pp)
      #pragma unroll
      for (int c2 = 0; c2 < 2; ++c2) {
        float v = fmaxf(fmaxf(acc[8*pp + 2*c2], acc[8*pp + 2*c2 + 1]),
                        fmaxf(acc[8*pp + 4 + 2*c2], acc[8*pp + 4 + 2*c2 + 1]));
        v += b1c; v = (v >= 0.f) ? v : a1 * v;
        int pr = (r0 >> 1) + pp, pc = (cc >> 1) + 2 * hf + c2;
        if (pc < 9) s2[((pr + 1) * 12 + (pc + 1)) * 40 + col] = (f16)v;
      }
  }
  __syncthreads();

  // ---- conv2+pool: 4 waves = (row-half mt, co-tile c2t); write h3f NHWC ----
  if (wv < 4) {
    const int mt = wv >> 1, c2t = wv & 1;
    const float a2 = a2p[0];
    const float b2c = b2[c2t * 32 + col];
    const f16* pA = s2 + ((mt * 4 + dr) * 12 + dc) * 40 + hf * 8;
    floatx16 acc = Z16;
    #pragma unroll 4
    for (int tap = 0; tap < 16; ++tap) {
      int aoff = ((tap >> 2) * 12 + (tap & 3)) * 40;
      #pragma unroll
      for (int ch = 0; ch < 2; ++ch) {
        half8 b = w2t8[tap * 256 + ch * 128 + c2t * 64 + hf * 32 + col];
        half8 a = *(const half8*)(pA + aoff + ch * 16);
        acc = __builtin_amdgcn_mfma_f32_32x32x16_f16(a, b, acc, 0, 0, 0);
      }
    }
    f16* o = h3f + n * 1024;
    #pragma unroll
    for (int pp = 0; pp < 2; ++pp)
      #pragma unroll
      for (int c2 = 0; c2 < 2; ++c2) {
        float v = fmaxf(fmaxf(acc[8*pp + 2*c2], acc[8*pp + 2*c2 + 1]),
                        fmaxf(acc[8*pp + 4 + 2*c2], acc[8*pp + 4 + 2*c2 + 1]));
        v += b2c; v = (v >= 0.f) ? v : a2 * v;
        int pr = mt * 2 + pp, pc = 2 * hf + c2;
        o[(pr * 4 + pc) * 64 + c2t * 32 + col] = (f16)v;
      }
  }
}

// ---------------- fused conv3 + fc1 + fc2 + fc3 (MFMA f16) ----------------
// grid 192: blockIdx -> landmark lm = b%6, image tile t = b/6 (16 images each;
// batch = t*16 + i). Was grid 96 x 32 images: only 37% of CUs had work and each block
// ran 1 wave/SIMD — k_tail is latency-bound on its conv3 gather loop, so double the
// block count. fc stages keep 32-row MFMA shapes: s_feat/s_g1/s_g2 rows 16..31 are
// garbage, but MFMA D rows 0..15 depend only on A rows 0..15; only `out` is guarded.
__global__ __launch_bounds__(256) void k_tail(
    const f16* __restrict__ h3f,
    const f16* __restrict__ w3t, const float* __restrict__ b3, const float* __restrict__ a3p,
    const f16* __restrict__ fc1t, const float* __restrict__ fc1b, const float* __restrict__ a4,
    const f16* __restrict__ fc2t, const float* __restrict__ fc2b, const float* __restrict__ a5,
    const f16* __restrict__ fc3t, const float* __restrict__ fc3b,
    float* __restrict__ out)
{
  __shared__ __align__(16) f16 s_feat[32 * 264];  // rows 0..15 valid; 16..31 don't-care
  __shared__ __align__(16) f16 s_g1[32 * 136];
  __shared__ __align__(16) f16 s_g2[32 * 72];

  const int lm = blockIdx.x % 6, t = blockIdx.x / 6;   // t in [0,32)
  const int tid = threadIdx.x, wv = tid >> 6, lane = tid & 63;
  const int hf = lane >> 5, col = lane & 31;
  const half8* w3t8  = (const half8*)w3t;
  const half8* fc1t8 = (const half8*)fc1t;
  const half8* fc2t8 = (const half8*)fc2t;
  const half8* fc3t8 = (const half8*)fc3t;

  // ---- conv3: wave = (image-octet mt, N-half ctw); M = 8img x 4pos = 32 rows; K=576 ----
  {
    const int mt = wv >> 1, ctw = wv & 1;
    const int i_img = mt * 8 + (col >> 2);             // 0..15
    const int pos = col & 3, oy = pos >> 1, ox = pos & 1;
    const int gimg = (t * 16 + i_img) * 6 + lm;
    const f16* Abase = h3f + gimg * 1024 + (oy * 4 + ox) * 64;
    floatx16 acc = Z16;
    for (int c = 0; c < 36; ++c) {
      int tap = c >> 2;
      int ky = tap / 3, kx = tap % 3;
      half8 a  = *(const half8*)(Abase + (ky * 4 + kx) * 64 + (c & 3) * 16 + hf * 8);
      half8 bb = w3t8[((c * 2 + ctw) * 2 + hf) * 32 + col];
      acc = __builtin_amdgcn_mfma_f32_32x32x16_f16(a, bb, acc, 0, 0, 0);
    }
    const float a3 = a3p[0];
    const int co = ctw * 32 + col;
    const float bbv = b3[co];
    #pragma unroll
    for (int q = 0; q < 4; ++q) {
      int ii = mt * 8 + 2 * q + hf;                    // 0..15
      half4 w;
      #pragma unroll
      for (int z = 0; z < 4; ++z) {
        float v = acc[q * 4 + z] + bbv;
        v = (v >= 0.f) ? v : a3 * v;
        w[z] = (f16)v;
      }
      *(half4*)(s_feat + ii * 264 + co * 4) = w;
    }
  }
  __syncthreads();

  // ---- fc1: M=16 imgs (rows 16..31 don't-care), K=256 (16 chunks), N=128; wave = N-tile ----
  {
    floatx16 g = Z16;
    for (int c = 0; c < 16; ++c) {
      half8 a = *(const half8*)(s_feat + col * 264 + c * 16 + hf * 8);
      half8 b = fc1t8[(((lm * 16 + c) * 4 + wv) * 2 + hf) * 32 + col];
      g = __builtin_amdgcn_mfma_f32_32x32x16_f16(a, b, g, 0, 0, 0);
    }
    const float a4v = a4[lm];
    const float bb = fc1b[lm * 128 + wv * 32 + col];
    #pragma unroll
    for (int reg = 0; reg < 16; ++reg) {
      int r = (reg & 3) + 8 * (reg >> 2) + 4 * hf;
      float v = g[reg] + bb;
      v = (v >= 0.f) ? v : a4v * v;
      s_g1[r * 136 + wv * 32 + col] = (f16)v;
    }
  }
  __syncthreads();

  // ---- fc2: K=128 (8 chunks), N=64; waves 0,1 ----
  if (wv < 2) {
    floatx16 g = Z16;
    for (int c = 0; c < 8; ++c) {
      half8 a = *(const half8*)(s_g1 + col * 136 + c * 16 + hf * 8);
      half8 b = fc2t8[(((lm * 8 + c) * 2 + wv) * 2 + hf) * 32 + col];
      g = __builtin_amdgcn_mfma_f32_32x32x16_f16(a, b, g, 0, 0, 0);
    }
    const float a5v = a5[lm];
    const float bb = fc2b[lm * 64 + wv * 32 + col];
    #pragma unroll
    for (int reg = 0; reg < 16; ++reg) {
      int r = (reg & 3) + 8 * (reg >> 2) + 4 * hf;
      float v = g[reg] + bb;
      v = (v >= 0.f) ? v : a5v * v;
      s_g2[r * 72 + wv * 32 + col] = (f16)v;
    }
  }
  __syncthreads();

  // ---- fc3: K=64 (4 chunks), N=4 (padded); wave 0; store rows < 16 only ----
  if (wv == 0) {
    floatx16 g = Z16;
    for (int c = 0; c < 4; ++c) {
      half8 a = *(const half8*)(s_g2 + col * 72 + c * 16 + hf * 8);
      half8 b = fc3t8[((lm * 4 + c) * 2 + hf) * 32 + col];
      g = __builtin_amdgcn_mfma_f32_32x32x16_f16(a, b, g, 0, 0, 0);
    }
    if (col < 4) {
      const float bb = fc3b[lm * 4 + col];
      #pragma unroll
      for (int reg = 0; reg < 16; ++reg) {
        int r = (reg & 3) + 8 * (reg >> 2) + 4 * hf;
        if (r < 16)
          out[((t * 16 + r) * 6 + lm) * 4 + col] = g[reg] + bb;
      }
    }
  }
}

extern "C" void kernel_launch(void* const* d_in, const int* in_sizes, int n_in,
                              void* d_out, int out_size, void* d_ws, size_t ws_size,
                              hipStream_t stream) {
  const float* x    = (const float*)d_in[0];
  const float* w0   = (const float*)d_in[1];
  const float* b0   = (const float*)d_in[2];
  const float* w1   = (const float*)d_in[3];
  const float* b1   = (const float*)d_in[4];
  const float* w2   = (const float*)d_in[5];
  const float* b2   = (const float*)d_in[6];
  const float* w3   = (const float*)d_in[7];
  const float* b3   = (const float*)d_in[8];
  const float* a0   = (const float*)d_in[9];
  const float* a1   = (const float*)d_in[10];
  const float* a2   = (const float*)d_in[11];
  const float* a3   = (const float*)d_in[12];
  const float* fc1w = (const float*)d_in[13];
  const float* fc1b = (const float*)d_in[14];
  const float* a4   = (const float*)d_in[15];
  const float* fc2w = (const float*)d_in[16];
  const float* fc2b = (const float*)d_in[17];
  const float* a5   = (const float*)d_in[18];
  const float* fc3w = (const float*)d_in[19];
  const float* fc3b = (const float*)d_in[20];
  float* out = (float*)d_out;

  char* ws = (char*)d_ws;
  f16* w0t  = (f16*)(ws + WS_W0T);
  f16* w1t  = (f16*)(ws + WS_W1T);
  f16* w2t  = (f16*)(ws + WS_W2T);
  f16* w3t  = (f16*)(ws + WS_W3T);
  f16* fc1t = (f16*)(ws + WS_FC1T);
  f16* fc2t = (f16*)(ws + WS_FC2T);
  f16* fc3t = (f16*)(ws + WS_FC3T);
  f16* h3f  = (f16*)(ws + WS_H3F);

  k_prep   <<<128, 256, 0, stream>>>(w0, w1, w2, w3, fc1w, fc2w, fc3w,
                                     w0t, w1t, w2t, w3t, fc1t, fc2t, fc3t);
  k_conv012<<<NIMG, 512, 0, stream>>>(x, w0t, b0, a0, w1t, b1, a1, w2t, b2, a2, h3f);
  k_tail   <<<192, 256, 0, stream>>>(h3f, w3t, b3, a3, fc1t, fc1b, a4,
                                     fc2t, fc2b, a5, fc3t, fc3b, out);
}